// Round 11
// baseline (590.133 us; speedup 1.0000x reference)
//
#include <hip/hip_runtime.h>
#include <hip/hip_bf16.h>
#include <cstdint>

namespace {

typedef __bf16 bf8v __attribute__((ext_vector_type(8)));
typedef __bf16 bf4v __attribute__((ext_vector_type(4)));
typedef float  f4v  __attribute__((ext_vector_type(4)));
typedef uint32_t u32x4 __attribute__((ext_vector_type(4)));

constexpr int kB = 128;   // batch
constexpr int kQ = 32;    // query len
constexpr int kD = 512;   // doc len
constexpr int kE = 300;   // embed dim
constexpr int kC = 128;   // conv channels
constexpr int kK = 11;    // RBF kernels

// workspace layout (bytes)
constexpr size_t QNB_B = 491520;
constexpr size_t DNB_B = 3637248;
constexpr size_t PKQ_B = 53968896;

constexpr float LOG2E = 1.4426950408889634f;

constexpr int XS_STRIDE = 336;   // elems; 672 B row stride
constexpr int TB_STRIDE = 136;   // tbuf row stride

// ---------------- weight repack to bf16 [chunk][c][32] ----------------
__global__ __launch_bounds__(256) void prep_kernel(
    const float* __restrict__ w1, const float* __restrict__ w2, const float* __restrict__ w3,
    __bf16* __restrict__ wb)
{
  int i = blockIdx.x * 256 + threadIdx.x;   // 0..245759
  if (i >= 245760) return;
  int el = i & 31;
  int sc = i >> 5;              // chunk*128 + c
  int c  = sc & 127;
  int chunk = sc >> 7;          // slab*10 + ks
  int slab = chunk / 10;
  int ks = chunk - slab * 10;
  int e = ks * 32 + el;
  float v = 0.f;
  if (e < kE) {
    if (slab == 0)      v = w1[c * kE + e];
    else if (slab <= 2) v = w2[(c * kE + e) * 2 + (slab - 1)];
    else                v = w3[(c * kE + e) * 3 + (slab - 3)];
  }
  wb[i] = (__bf16)v;
}

// -------- counted-vmcnt async load machinery; loads are CLOBBER-FREE (fix) --------
template<int V>
__device__ __forceinline__ void wv() {
  if constexpr (V == 5) asm volatile("s_waitcnt vmcnt(0)" ::: "memory");
  else                  asm volatile("s_waitcnt vmcnt(2)" ::: "memory");
  __builtin_amdgcn_sched_barrier(0);
}

__device__ __forceinline__ void issue2(u32x4 (&Wset)[2], const __bf16* p) {
  asm volatile("global_load_dwordx4 %0, %1, off"             : "=v"(Wset[0]) : "v"(p));
  asm volatile("global_load_dwordx4 %0, %1, off offset:1024" : "=v"(Wset[1]) : "v"(p));
}

// V==2: sink operands, no MFMA (keeps loads/ds_reads live per rule #17)
template<int V>
__device__ __forceinline__ void use_batch(bf8v A0, bf8v A1, u32x4 (&Ws)[2], f4v (&acc)[2][2]) {
  if constexpr (V == 2) {
    asm volatile("" :: "v"(A0), "v"(A1), "v"(Ws[0]), "v"(Ws[1]));
  } else {
    #pragma unroll
    for (int nf = 0; nf < 2; ++nf) {
      bf8v Wf = __builtin_bit_cast(bf8v, Ws[nf]);
      acc[0][nf] = __builtin_amdgcn_mfma_f32_16x16x32_bf16(A0, Wf, acc[0][nf], 0, 0, 0);
      acc[1][nf] = __builtin_amdgcn_mfma_f32_16x16x32_bf16(A1, Wf, acc[1][nf], 0, 0, 0);
    }
  }
}

// ---------------- per-grp loop: depth-2 register pipeline, rolled, no barriers ----------------
// V: 0 full | 1 no W loads | 2 no MFMA | 3 const A (no ds_read) | 4 full loop (epi skipped) | 5 drain waits
template<int V, int NJ, int CH0>
__device__ __forceinline__ void conv_grp(
    const __bf16* __restrict__ wb, const __bf16* __restrict__ Xs,
    int w, int lr, int g, f4v (&acc)[2][2])
{
  const __bf16* wl = wb + (size_t)CH0 * 4096 + (w * 32 + lr) * 32 + g * 8;
  const int ae = g * 8;

  u32x4 W0[2], W1[2];
  if constexpr (V != 1) {
    issue2(W0, wl);            // batch 0
    issue2(W1, wl + 4096);     // batch 1
  } else {
    W0[0] = (u32x4)(uint32_t)(w * 64 + lr);
    W0[1] = W0[0]; W1[0] = W0[0]; W1[1] = W0[0];
  }
  const __bf16* wnext = wl + 2 * 4096;

  #pragma unroll
  for (int j = 0; j < NJ; ++j) {
    const __bf16* xr = Xs + (size_t)(lr + j) * XS_STRIDE + ae;
    const int nks = (j == NJ - 1) ? 8 : 10;   // last j leaves 2 drain steps
    #pragma unroll 1
    for (int ks = 0; ks < nks; ks += 2) {
      bf8v A0, A1, B0, B1;
      if constexpr (V == 3) { A0 = (bf8v)(__bf16)0.5f; A1 = A0; }
      else {
        A0 = *(const bf8v*)(xr + ks * 32);
        A1 = *(const bf8v*)(xr + 16 * XS_STRIDE + ks * 32);
      }
      if constexpr (V != 1) wv<V>();
      use_batch<V>(A0, A1, W0, acc);
      if constexpr (V != 1) { issue2(W0, wnext); wnext += 4096; }
      if constexpr (V == 3) { B0 = (bf8v)(__bf16)0.5f; B1 = B0; }
      else {
        B0 = *(const bf8v*)(xr + ks * 32 + 32);
        B1 = *(const bf8v*)(xr + 16 * XS_STRIDE + ks * 32 + 32);
      }
      if constexpr (V != 1) wv<V>();
      use_batch<V>(B0, B1, W1, acc);
      if constexpr (V != 1) { issue2(W1, wnext); wnext += 4096; }
    }
  }
  // drain: steps ks=8,9 of last j
  const __bf16* xr = Xs + (size_t)(lr + NJ - 1) * XS_STRIDE + ae;
  bf8v A0, A1, B0, B1;
  if constexpr (V == 3) { A0 = (bf8v)(__bf16)0.5f; A1 = A0; }
  else { A0 = *(const bf8v*)(xr + 8 * 32); A1 = *(const bf8v*)(xr + 16 * XS_STRIDE + 8 * 32); }
  if constexpr (V != 1) wv<V>();
  use_batch<V>(A0, A1, W0, acc);
  if constexpr (V == 3) { B0 = (bf8v)(__bf16)0.5f; B1 = B0; }
  else { B0 = *(const bf8v*)(xr + 9 * 32); B1 = *(const bf8v*)(xr + 16 * XS_STRIDE + 9 * 32); }
  if constexpr (V != 1) {
    asm volatile("s_waitcnt vmcnt(0)" ::: "memory");
    __builtin_amdgcn_sched_barrier(0);
  }
  use_batch<V>(B0, B1, W1, acc);
}

// ---------------- fused conv template (V per ablation) ----------------
// grid (17, B): x==0 -> query (32 pos), x=1..16 -> doc tile p0=(x-1)*32
template<int V>
__global__ __launch_bounds__(256, 5) void conv_fused(
    const float* __restrict__ qe, const float* __restrict__ de,
    const __bf16* __restrict__ wb,
    const float* __restrict__ b1, const float* __restrict__ b2, const float* __restrict__ b3,
    __bf16* __restrict__ qnb, __bf16* __restrict__ dnb)
{
  const int bx = blockIdx.x;
  const int b  = blockIdx.y;
  const bool isq = (bx == 0);
  const int L  = isq ? kQ : kD;
  const int p0 = isq ? 0 : (bx - 1) * 32;
  const float* xsrc = (isq ? qe : de) + (size_t)b * L * kE;

  const int t = threadIdx.x;
  const int w = t >> 6, l = t & 63;
  const int lr = l & 15, g = l >> 4;

  __shared__ __align__(16) __bf16 Xs[34 * XS_STRIDE];
  __shared__ __align__(16) __bf16 tbuf[32 * TB_STRIDE];
  __shared__ float sqs4[4][32];

  // stage x rows p0..p0+33, e 0..327 (zero-pad) as bf16
  for (int idx = t; idx < 34 * 82; idx += 256) {
    int row = idx / 82, c4 = idx - row * 82;
    int gp = p0 + row;
    float4 v = make_float4(0.f, 0.f, 0.f, 0.f);
    if (gp < L && c4 < 75) v = *(const float4*)(xsrc + (size_t)gp * kE + c4 * 4);
    bf4v hv = { (__bf16)v.x, (__bf16)v.y, (__bf16)v.z, (__bf16)v.w };
    *(bf4v*)&Xs[row * XS_STRIDE + c4 * 4] = hv;
  }
  __syncthreads();

  #pragma unroll
  for (int grp = 0; grp < 3; ++grp) {
    f4v acc[2][2];
    #pragma unroll
    for (int mf = 0; mf < 2; ++mf)
      #pragma unroll
      for (int nf = 0; nf < 2; ++nf)
        acc[mf][nf] = (f4v)0.f;

    if (grp == 0)      conv_grp<V, 1, 0>(wb, Xs, w, lr, g, acc);
    else if (grp == 1) conv_grp<V, 2, 10>(wb, Xs, w, lr, g, acc);
    else               conv_grp<V, 3, 30>(wb, Xs, w, lr, g, acc);

    if constexpr (V == 4) {
      // no epilogue: sink accumulators so the loop stays live
      #pragma unroll
      for (int mf = 0; mf < 2; ++mf)
        #pragma unroll
        for (int nf = 0; nf < 2; ++nf)
          asm volatile("" :: "v"(acc[mf][nf]));
    } else {
      // epilogue: bias + relu + L2 norm over 128 channels (cross-wave via sqs4)
      const float* bias = (grp == 0) ? b1 : ((grp == 1) ? b2 : b3);
      float bvs[2];
      #pragma unroll
      for (int nf = 0; nf < 2; ++nf) bvs[nf] = bias[w * 32 + nf * 16 + lr];

      f4v ssum[2];
      #pragma unroll
      for (int mf = 0; mf < 2; ++mf) {
        ssum[mf] = (f4v)0.f;
        #pragma unroll
        for (int nf = 0; nf < 2; ++nf)
          #pragma unroll
          for (int r = 0; r < 4; ++r) {
            float y = fmaxf(acc[mf][nf][r] + bvs[nf], 0.f);
            acc[mf][nf][r] = y;
            ssum[mf][r] += y * y;
          }
      }
      #pragma unroll
      for (int off = 1; off < 16; off <<= 1)
        #pragma unroll
        for (int mf = 0; mf < 2; ++mf)
          #pragma unroll
          for (int r = 0; r < 4; ++r)
            ssum[mf][r] += __shfl_xor(ssum[mf][r], off);

      if (lr == 0) {
        #pragma unroll
        for (int mf = 0; mf < 2; ++mf)
          *(float4*)&sqs4[w][mf * 16 + g * 4] = *(float4*)&ssum[mf];
      }
      __syncthreads();
      float inv[2][4];
      #pragma unroll
      for (int mf = 0; mf < 2; ++mf)
        #pragma unroll
        for (int r = 0; r < 4; ++r) {
          int row = mf * 16 + g * 4 + r;
          float s = sqs4[0][row] + sqs4[1][row] + sqs4[2][row] + sqs4[3][row];
          inv[mf][r] = 1.f / (sqrtf(s) + 1e-13f);
        }
      #pragma unroll
      for (int mf = 0; mf < 2; ++mf)
        #pragma unroll
        for (int nf = 0; nf < 2; ++nf)
          #pragma unroll
          for (int r = 0; r < 4; ++r) {
            int row = mf * 16 + g * 4 + r;
            int c = w * 32 + nf * 16 + lr;
            tbuf[row * TB_STRIDE + c] = (__bf16)(acc[mf][nf][r] * inv[mf][r]);
          }
      __syncthreads();
      __bf16* outp = (isq ? qnb : dnb) + ((size_t)(grp * kB + b)) * L * kC + (size_t)p0 * kC;
      #pragma unroll
      for (int ci = t; ci < 512; ci += 256) {
        bf8v v = *(const bf8v*)&tbuf[(ci >> 4) * TB_STRIDE + (ci & 15) * 8];
        *(bf8v*)(outp + ci * 8) = v;
      }
      asm volatile("s_waitcnt vmcnt(0)" ::: "memory");   // keep counted waits clean next grp
      __syncthreads();
    }
  }
}

// ---------------- MFMA cosine + RBF pooling ----------------
__global__ __launch_bounds__(256) void pool_mfma(
    const __bf16* __restrict__ qnb,  // [3][B][32][128]
    const __bf16* __restrict__ dnb,  // [3][B][512][128]
    const float* __restrict__ qmask, // [B][32]
    const float* __restrict__ dmask, // [B][512]
    float* __restrict__ pkq)         // [9][B][32][11]
{
  const int pair = blockIdx.x;
  const int b = blockIdx.y;
  const int qi = pair / 3, dj = pair - qi * 3;
  const __bf16* qb = qnb + ((size_t)qi * kB + b) * kQ * kC;
  const __bf16* db = dnb + ((size_t)dj * kB + b) * kD * kC;

  const int t = threadIdx.x;
  const int w = t >> 6, l = t & 63;
  const int lr = l & 15, g = l >> 4;

  __shared__ float red[4][2][16][kK];

  bf8v Bq[2][4];
  #pragma unroll
  for (int qt = 0; qt < 2; ++qt)
    #pragma unroll
    for (int kc = 0; kc < 4; ++kc)
      Bq[qt][kc] = *(const bf8v*)&qb[(size_t)(qt * 16 + lr) * kC + kc * 32 + g * 8];

  float qmv[2];
  #pragma unroll
  for (int qt = 0; qt < 2; ++qt) qmv[qt] = qmask[b * kQ + qt * 16 + lr];

  const float c1[10] = { 129.84255368f, 100.98865286f,  72.13475204f,  43.28085123f,  14.42695041f,
                         -14.42695041f, -43.28085123f, -72.13475204f, -100.98865286f, -129.84255368f };
  const float c2[10] = { -58.42914915f, -35.34602850f, -18.03368801f, -6.49212768f, -0.72134752f,
                          -0.72134752f,  -6.49212768f, -18.03368801f, -35.34602850f, -58.42914915f };
  const float C50 = -50.f * LOG2E;
  const float C0  = -500000.f * LOG2E;

  float pk[2][kK];
  #pragma unroll
  for (int qt = 0; qt < 2; ++qt)
    #pragma unroll
    for (int k = 0; k < kK; ++k) pk[qt][k] = 0.f;

  const int dt0 = w * 8;
  bf8v An[4];
  #pragma unroll
  for (int kc = 0; kc < 4; ++kc)
    An[kc] = *(const bf8v*)&db[(size_t)(dt0 * 16 + lr) * kC + kc * 32 + g * 8];

  for (int dtl = 0; dtl < 8; ++dtl) {
    const int drow0 = (dt0 + dtl) * 16;
    bf8v Ac[4];
    #pragma unroll
    for (int kc = 0; kc < 4; ++kc) Ac[kc] = An[kc];
    if (dtl < 7) {
      #pragma unroll
      for (int kc = 0; kc < 4; ++kc)
        An[kc] = *(const bf8v*)&db[(size_t)(drow0 + 16 + lr) * kC + kc * 32 + g * 8];
    }
    f4v acc0 = (f4v)0.f, acc1 = (f4v)0.f;
    #pragma unroll
    for (int kc = 0; kc < 4; ++kc) {
      acc0 = __builtin_amdgcn_mfma_f32_16x16x32_bf16(Ac[kc], Bq[0][kc], acc0, 0, 0, 0);
      acc1 = __builtin_amdgcn_mfma_f32_16x16x32_bf16(Ac[kc], Bq[1][kc], acc1, 0, 0, 0);
    }
    float4 dmv = *(const float4*)&dmask[b * kD + drow0 + g * 4];
    #pragma unroll
    for (int qt = 0; qt < 2; ++qt) {
      const f4v& a = qt ? acc1 : acc0;
      #pragma unroll
      for (int r = 0; r < 4; ++r) {
        float dm = (r == 0) ? dmv.x : (r == 1) ? dmv.y : (r == 2) ? dmv.z : dmv.w;
        float off = fmaf(dm, 1000.f, -1000.f);
        float s = a[r] * qmv[qt] * dm;
        float s2 = s * s;
        float base = fmaf(s2, C50, off);
        float dd = s - 1.f;
        pk[qt][0] += exp2f(fmaf(dd * dd, C0, off));
        #pragma unroll
        for (int k = 0; k < 10; ++k)
          pk[qt][k + 1] += exp2f(fmaf(c1[k], s, base) + c2[k]);
      }
    }
  }

  #pragma unroll
  for (int off = 16; off < 64; off <<= 1)
    #pragma unroll
    for (int qt = 0; qt < 2; ++qt)
      #pragma unroll
      for (int k = 0; k < kK; ++k)
        pk[qt][k] += __shfl_xor(pk[qt][k], off);

  if (l < 16) {
    #pragma unroll
    for (int qt = 0; qt < 2; ++qt)
      #pragma unroll
      for (int k = 0; k < kK; ++k)
        red[w][qt][lr][k] = pk[qt][k];
  }
  __syncthreads();
  for (int i = t; i < 2 * 16 * kK; i += 256) {
    int qt = i / (16 * kK);
    int rem = i - qt * 16 * kK;
    int lq = rem / kK, k = rem - lq * kK;
    float v = red[0][qt][lq][k] + red[1][qt][lq][k] + red[2][qt][lq][k] + red[3][qt][lq][k];
    int q = qt * 16 + lq;
    pkq[(((size_t)pair * kB + b) * kQ + q) * kK + k] = v * qmask[b * kQ + q];
  }
}

// ---------------- log-pool + dense layers ----------------
__global__ __launch_bounds__(128) void finalize_kernel(
    const float* __restrict__ pkq, const float* __restrict__ qmask,
    const float* __restrict__ dmask, const float* __restrict__ nsp,
    const float* __restrict__ dw, const float* __restrict__ dbp,
    const float* __restrict__ dmw, const float* __restrict__ dmbp,
    const float* __restrict__ dcw, float* __restrict__ out)
{
  const int b = blockIdx.x;
  const int t = threadIdx.x;
  __shared__ float sh[4];
  float dl = 0.f;
  for (int d = t; d < kD; d += 128) dl += dmask[b * kD + d];
  #pragma unroll
  for (int off = 1; off < 64; off <<= 1) dl += __shfl_xor(dl, off);
  if ((t & 63) == 0) sh[t >> 6] = dl;
  __syncthreads();
  const float idl = 1.f / (sh[0] + sh[1]);
  const float sc = nsp[0];
  float ps = 0.f, pm = 0.f;
  for (int i = t; i < 99; i += 128) {
    int pr = i / kK, kk = i - pr * kK;
    const float* base = pkq + ((size_t)pr * kB + b) * kQ * kK + kk;
    float ss = 0.f, sm = 0.f;
    for (int q = 0; q < kQ; ++q) {
      float v = base[q * kK];
      float qq = qmask[b * kQ + q];
      ss += __logf(fmaxf(v, 1e-10f)) * qq;
      sm += __logf(fmaxf(v * idl, 1e-10f)) * qq;
    }
    ps += dw[i] * ss;
    pm += dmw[i] * sm;
  }
  ps *= sc; pm *= sc;
  #pragma unroll
  for (int off = 1; off < 64; off <<= 1) { ps += __shfl_xor(ps, off); pm += __shfl_xor(pm, off); }
  __syncthreads();
  if ((t & 63) == 0) { sh[t >> 6] = ps; sh[2 + (t >> 6)] = pm; }
  __syncthreads();
  if (t == 0) {
    float PS = sh[0] + sh[1] + dbp[0];
    float PM = sh[2] + sh[3] + dmbp[0];
    out[b] = dcw[0] * PS + dcw[1] * PM;
  }
}

} // namespace

extern "C" void kernel_launch(void* const* d_in, const int* in_sizes, int n_in,
                              void* d_out, int out_size, void* d_ws, size_t ws_size,
                              hipStream_t stream) {
  const float* qe  = (const float*)d_in[0];
  const float* de  = (const float*)d_in[1];
  const float* qm  = (const float*)d_in[2];
  const float* dm  = (const float*)d_in[3];
  const float* w1  = (const float*)d_in[4];
  const float* b1  = (const float*)d_in[5];
  const float* w2  = (const float*)d_in[6];
  const float* b2  = (const float*)d_in[7];
  const float* w3  = (const float*)d_in[8];
  const float* b3  = (const float*)d_in[9];
  const float* ns  = (const float*)d_in[10];
  const float* dw  = (const float*)d_in[11];
  const float* db  = (const float*)d_in[12];
  const float* dmw = (const float*)d_in[13];
  const float* dmb = (const float*)d_in[14];
  const float* dcw = (const float*)d_in[15];
  float* out = (float*)d_out;

  char* wsb = (char*)d_ws;
  __bf16* wb  = (__bf16*)wsb;
  __bf16* qnb = (__bf16*)(wsb + QNB_B);
  __bf16* dnb = (__bf16*)(wsb + DNB_B);
  float*  pkq = (float*)(wsb + PKQ_B);

  prep_kernel<<<960, 256, 0, stream>>>(w1, w2, w3, wb);

  // --- ablation dispatches (outputs fully overwritten by the real V0 run below) ---
  conv_fused<1><<<dim3(17, kB), 256, 0, stream>>>(qe, de, wb, b1, b2, b3, qnb, dnb); // no W loads
  conv_fused<2><<<dim3(17, kB), 256, 0, stream>>>(qe, de, wb, b1, b2, b3, qnb, dnb); // no MFMA
  conv_fused<3><<<dim3(17, kB), 256, 0, stream>>>(qe, de, wb, b1, b2, b3, qnb, dnb); // no A ds_read
  conv_fused<4><<<dim3(17, kB), 256, 0, stream>>>(qe, de, wb, b1, b2, b3, qnb, dnb); // no epilogue
  conv_fused<5><<<dim3(17, kB), 256, 0, stream>>>(qe, de, wb, b1, b2, b3, qnb, dnb); // drain vmcnt(0)
  // --- real conv (clobber-free counted-vmcnt), runs last -> correct outputs ---
  conv_fused<0><<<dim3(17, kB), 256, 0, stream>>>(qe, de, wb, b1, b2, b3, qnb, dnb);

  pool_mfma<<<dim3(9, kB), 256, 0, stream>>>(qnb, dnb, qm, dm, pkq);
  finalize_kernel<<<kB, 128, 0, stream>>>(pkq, qm, dm, ns, dw, db, dmw, dmb, dcw, out);
}

// Round 12
// 167.721 us; speedup vs baseline: 3.5185x; 3.5185x over previous
//
#include <hip/hip_runtime.h>
#include <hip/hip_bf16.h>
#include <cstdint>

namespace {

typedef __bf16 bf8v __attribute__((ext_vector_type(8)));
typedef __bf16 bf4v __attribute__((ext_vector_type(4)));
typedef float  f4v  __attribute__((ext_vector_type(4)));
typedef uint32_t u32x4 __attribute__((ext_vector_type(4)));

constexpr int kB = 128;   // batch
constexpr int kQ = 32;    // query len
constexpr int kD = 512;   // doc len
constexpr int kE = 300;   // embed dim
constexpr int kC = 128;   // conv channels
constexpr int kK = 11;    // RBF kernels

// workspace layout (bytes)
constexpr size_t QNB_B = 491520;
constexpr size_t DNB_B = 3637248;
constexpr size_t PKQ_B = 53968896;

constexpr float LOG2E = 1.4426950408889634f;

constexpr int XS_STRIDE = 336;   // elems; 672 B row stride
constexpr int TB_STRIDE = 136;   // tbuf row stride

// ---------------- weight repack to bf16 [chunk][c][32] ----------------
__global__ __launch_bounds__(256) void prep_kernel(
    const float* __restrict__ w1, const float* __restrict__ w2, const float* __restrict__ w3,
    __bf16* __restrict__ wb)
{
  int i = blockIdx.x * 256 + threadIdx.x;   // 0..245759
  if (i >= 245760) return;
  int el = i & 31;
  int sc = i >> 5;              // chunk*128 + c
  int c  = sc & 127;
  int chunk = sc >> 7;          // slab*10 + ks
  int slab = chunk / 10;
  int ks = chunk - slab * 10;
  int e = ks * 32 + el;
  float v = 0.f;
  if (e < kE) {
    if (slab == 0)      v = w1[c * kE + e];
    else if (slab <= 2) v = w2[(c * kE + e) * 2 + (slab - 1)];
    else                v = w3[(c * kE + e) * 3 + (slab - 3)];
  }
  wb[i] = (__bf16)v;
}

// -------- counted-vmcnt machinery: clobber-free loads, exact-count waits --------
__device__ __forceinline__ void wait_vmc(int n) {   // n is compile-time after unroll
  if (n >= 8)      asm volatile("s_waitcnt vmcnt(8)" ::: "memory");
  else if (n == 6) asm volatile("s_waitcnt vmcnt(6)" ::: "memory");
  else if (n == 4) asm volatile("s_waitcnt vmcnt(4)" ::: "memory");
  else if (n == 2) asm volatile("s_waitcnt vmcnt(2)" ::: "memory");
  else             asm volatile("s_waitcnt vmcnt(0)" ::: "memory");
  __builtin_amdgcn_sched_barrier(0);
}

__device__ __forceinline__ void issue2(u32x4 (&Wset)[2], const __bf16* p) {
  asm volatile("global_load_dwordx4 %0, %1, off"             : "=v"(Wset[0]) : "v"(p));
  asm volatile("global_load_dwordx4 %0, %1, off offset:1024" : "=v"(Wset[1]) : "v"(p));
}

__device__ __forceinline__ void mfma4(bf8v A0, bf8v A1, u32x4 (&Ws)[2], f4v (&acc)[2][2]) {
  #pragma unroll
  for (int nf = 0; nf < 2; ++nf) {
    bf8v Wf = __builtin_bit_cast(bf8v, Ws[nf]);
    acc[0][nf] = __builtin_amdgcn_mfma_f32_16x16x32_bf16(A0, Wf, acc[0][nf], 0, 0, 0);
    acc[1][nf] = __builtin_amdgcn_mfma_f32_16x16x32_bf16(A1, Wf, acc[1][nf], 0, 0, 0);
  }
}

// ---------------- per-grp loop: depth-5 W pipeline + depth-1 A prefetch ----------------
// fully unrolled -> W[s%5] and all offsets are compile-time. Tail waits 8/6/4/2/0.
template<int NJ, int CH0>
__device__ __forceinline__ void conv_grp(
    const __bf16* __restrict__ wb, const __bf16* __restrict__ Xs,
    int w, int lr, int g, f4v (&acc)[2][2])
{
  constexpr int N = NJ * 10;
  const __bf16* wl = wb + (size_t)CH0 * 4096 + (w * 32 + lr) * 32 + g * 8;
  const __bf16* xb0 = Xs + (size_t)lr * XS_STRIDE + g * 8;
  const __bf16* xb1 = xb0 + 16 * XS_STRIDE;

  u32x4 W[5][2];
  #pragma unroll
  for (int p = 0; p < 5 && p < N; ++p) issue2(W[p], wl + (size_t)p * 4096);

  bf8v Ac0 = *(const bf8v*)xb0;
  bf8v Ac1 = *(const bf8v*)xb1;

  #pragma unroll
  for (int s = 0; s < N; ++s) {
    bf8v An0, An1;
    if (s + 1 < N) {
      const int j1 = (s + 1) / 10, k1 = (s + 1) - ((s + 1) / 10) * 10;
      An0 = *(const bf8v*)(xb0 + j1 * XS_STRIDE + k1 * 32);
      An1 = *(const bf8v*)(xb1 + j1 * XS_STRIDE + k1 * 32);
    }
    const int rem = N - s;
    wait_vmc(rem >= 5 ? 8 : 2 * rem - 2);
    mfma4(Ac0, Ac1, W[s % 5], acc);
    if (s + 5 < N) issue2(W[s % 5], wl + (size_t)(s + 5) * 4096);
    Ac0 = An0; Ac1 = An1;
  }
}

// ---------------- fused conv (all 3 widths) + bias + relu + L2-norm -> bf16 [L][C] ----------------
// grid (17, B): x==0 -> query (32 pos), x=1..16 -> doc tile p0=(x-1)*32
// 256 threads = 4 waves; tile 32 pos x 128 ch; wave w -> all 32 pos, ch [w*32, w*32+32)
__global__ __launch_bounds__(256, 4) void conv_fused(
    const float* __restrict__ qe, const float* __restrict__ de,
    const __bf16* __restrict__ wb,
    const float* __restrict__ b1, const float* __restrict__ b2, const float* __restrict__ b3,
    __bf16* __restrict__ qnb, __bf16* __restrict__ dnb)
{
  const int bx = blockIdx.x;
  const int b  = blockIdx.y;
  const bool isq = (bx == 0);
  const int L  = isq ? kQ : kD;
  const int p0 = isq ? 0 : (bx - 1) * 32;
  const float* xsrc = (isq ? qe : de) + (size_t)b * L * kE;

  const int t = threadIdx.x;
  const int w = t >> 6, l = t & 63;
  const int lr = l & 15, g = l >> 4;

  __shared__ __align__(16) __bf16 Xs[34 * XS_STRIDE];
  __shared__ __align__(16) __bf16 tbuf[32 * TB_STRIDE];
  __shared__ float sqs4[4][32];

  // stage x rows p0..p0+33, e 0..327 (zero-pad) as bf16
  for (int idx = t; idx < 34 * 82; idx += 256) {
    int row = idx / 82, c4 = idx - row * 82;
    int gp = p0 + row;
    float4 v = make_float4(0.f, 0.f, 0.f, 0.f);
    if (gp < L && c4 < 75) v = *(const float4*)(xsrc + (size_t)gp * kE + c4 * 4);
    bf4v hv = { (__bf16)v.x, (__bf16)v.y, (__bf16)v.z, (__bf16)v.w };
    *(bf4v*)&Xs[row * XS_STRIDE + c4 * 4] = hv;
  }
  __syncthreads();

  #pragma unroll
  for (int grp = 0; grp < 3; ++grp) {
    f4v acc[2][2];
    #pragma unroll
    for (int mf = 0; mf < 2; ++mf)
      #pragma unroll
      for (int nf = 0; nf < 2; ++nf)
        acc[mf][nf] = (f4v)0.f;

    if (grp == 0)      conv_grp<1, 0>(wb, Xs, w, lr, g, acc);
    else if (grp == 1) conv_grp<2, 10>(wb, Xs, w, lr, g, acc);
    else               conv_grp<3, 30>(wb, Xs, w, lr, g, acc);

    // epilogue: bias + relu + L2 norm over 128 channels (cross-wave via sqs4)
    const float* bias = (grp == 0) ? b1 : ((grp == 1) ? b2 : b3);
    float bvs[2];
    #pragma unroll
    for (int nf = 0; nf < 2; ++nf) bvs[nf] = bias[w * 32 + nf * 16 + lr];

    f4v ssum[2];
    #pragma unroll
    for (int mf = 0; mf < 2; ++mf) {
      ssum[mf] = (f4v)0.f;
      #pragma unroll
      for (int nf = 0; nf < 2; ++nf)
        #pragma unroll
        for (int r = 0; r < 4; ++r) {
          float y = fmaxf(acc[mf][nf][r] + bvs[nf], 0.f);
          acc[mf][nf][r] = y;
          ssum[mf][r] += y * y;
        }
    }
    #pragma unroll
    for (int off = 1; off < 16; off <<= 1)
      #pragma unroll
      for (int mf = 0; mf < 2; ++mf)
        #pragma unroll
        for (int r = 0; r < 4; ++r)
          ssum[mf][r] += __shfl_xor(ssum[mf][r], off);

    if (lr == 0) {
      #pragma unroll
      for (int mf = 0; mf < 2; ++mf)
        *(float4*)&sqs4[w][mf * 16 + g * 4] = *(float4*)&ssum[mf];
    }
    __syncthreads();
    float inv[2][4];
    #pragma unroll
    for (int mf = 0; mf < 2; ++mf)
      #pragma unroll
      for (int r = 0; r < 4; ++r) {
        int row = mf * 16 + g * 4 + r;
        float s = sqs4[0][row] + sqs4[1][row] + sqs4[2][row] + sqs4[3][row];
        inv[mf][r] = 1.f / (sqrtf(s) + 1e-13f);
      }
    // normalized tile -> tbuf (row-major, padded stride)
    #pragma unroll
    for (int mf = 0; mf < 2; ++mf)
      #pragma unroll
      for (int nf = 0; nf < 2; ++nf)
        #pragma unroll
        for (int r = 0; r < 4; ++r) {
          int row = mf * 16 + g * 4 + r;
          int c = w * 32 + nf * 16 + lr;
          tbuf[row * TB_STRIDE + c] = (__bf16)(acc[mf][nf][r] * inv[mf][r]);
        }
    __syncthreads();
    // coalesced store: 512 x 16B contiguous
    __bf16* outp = (isq ? qnb : dnb) + ((size_t)(grp * kB + b)) * L * kC + (size_t)p0 * kC;
    #pragma unroll
    for (int ci = t; ci < 512; ci += 256) {
      bf8v v = *(const bf8v*)&tbuf[(ci >> 4) * TB_STRIDE + (ci & 15) * 8];
      *(bf8v*)(outp + ci * 8) = v;
    }
    asm volatile("s_waitcnt vmcnt(0)" ::: "memory");   // keep counted waits clean next grp
    __syncthreads();
  }
}

// ---------------- MFMA cosine + RBF pooling ----------------
// grid (9, B), 256 threads = 4 waves. Per block: S[512 d][32 q] for one (pair,b).
__global__ __launch_bounds__(256) void pool_mfma(
    const __bf16* __restrict__ qnb,  // [3][B][32][128]
    const __bf16* __restrict__ dnb,  // [3][B][512][128]
    const float* __restrict__ qmask, // [B][32]
    const float* __restrict__ dmask, // [B][512]
    float* __restrict__ pkq)         // [9][B][32][11]
{
  const int pair = blockIdx.x;
  const int b = blockIdx.y;
  const int qi = pair / 3, dj = pair - qi * 3;
  const __bf16* qb = qnb + ((size_t)qi * kB + b) * kQ * kC;
  const __bf16* db = dnb + ((size_t)dj * kB + b) * kD * kC;

  const int t = threadIdx.x;
  const int w = t >> 6, l = t & 63;
  const int lr = l & 15, g = l >> 4;

  __shared__ float red[4][2][16][kK];

  bf8v Bq[2][4];
  #pragma unroll
  for (int qt = 0; qt < 2; ++qt)
    #pragma unroll
    for (int kc = 0; kc < 4; ++kc)
      Bq[qt][kc] = *(const bf8v*)&qb[(size_t)(qt * 16 + lr) * kC + kc * 32 + g * 8];

  float qmv[2];
  #pragma unroll
  for (int qt = 0; qt < 2; ++qt) qmv[qt] = qmask[b * kQ + qt * 16 + lr];

  const float c1[10] = { 129.84255368f, 100.98865286f,  72.13475204f,  43.28085123f,  14.42695041f,
                         -14.42695041f, -43.28085123f, -72.13475204f, -100.98865286f, -129.84255368f };
  const float c2[10] = { -58.42914915f, -35.34602850f, -18.03368801f, -6.49212768f, -0.72134752f,
                          -0.72134752f,  -6.49212768f, -18.03368801f, -35.34602850f, -58.42914915f };
  const float C50 = -50.f * LOG2E;
  const float C0  = -500000.f * LOG2E;

  float pk[2][kK];
  #pragma unroll
  for (int qt = 0; qt < 2; ++qt)
    #pragma unroll
    for (int k = 0; k < kK; ++k) pk[qt][k] = 0.f;

  const int dt0 = w * 8;
  bf8v An[4];
  #pragma unroll
  for (int kc = 0; kc < 4; ++kc)
    An[kc] = *(const bf8v*)&db[(size_t)(dt0 * 16 + lr) * kC + kc * 32 + g * 8];

  for (int dtl = 0; dtl < 8; ++dtl) {
    const int drow0 = (dt0 + dtl) * 16;
    bf8v Ac[4];
    #pragma unroll
    for (int kc = 0; kc < 4; ++kc) Ac[kc] = An[kc];
    if (dtl < 7) {
      #pragma unroll
      for (int kc = 0; kc < 4; ++kc)
        An[kc] = *(const bf8v*)&db[(size_t)(drow0 + 16 + lr) * kC + kc * 32 + g * 8];
    }
    f4v acc0 = (f4v)0.f, acc1 = (f4v)0.f;
    #pragma unroll
    for (int kc = 0; kc < 4; ++kc) {
      acc0 = __builtin_amdgcn_mfma_f32_16x16x32_bf16(Ac[kc], Bq[0][kc], acc0, 0, 0, 0);
      acc1 = __builtin_amdgcn_mfma_f32_16x16x32_bf16(Ac[kc], Bq[1][kc], acc1, 0, 0, 0);
    }
    float4 dmv = *(const float4*)&dmask[b * kD + drow0 + g * 4];
    #pragma unroll
    for (int qt = 0; qt < 2; ++qt) {
      const f4v& a = qt ? acc1 : acc0;
      #pragma unroll
      for (int r = 0; r < 4; ++r) {
        float dm = (r == 0) ? dmv.x : (r == 1) ? dmv.y : (r == 2) ? dmv.z : dmv.w;
        float off = fmaf(dm, 1000.f, -1000.f);
        float s = a[r] * qmv[qt] * dm;
        float s2 = s * s;
        float base = fmaf(s2, C50, off);
        float dd = s - 1.f;
        pk[qt][0] += exp2f(fmaf(dd * dd, C0, off));
        #pragma unroll
        for (int k = 0; k < 10; ++k)
          pk[qt][k + 1] += exp2f(fmaf(c1[k], s, base) + c2[k]);
      }
    }
  }

  #pragma unroll
  for (int off = 16; off < 64; off <<= 1)
    #pragma unroll
    for (int qt = 0; qt < 2; ++qt)
      #pragma unroll
      for (int k = 0; k < kK; ++k)
        pk[qt][k] += __shfl_xor(pk[qt][k], off);

  if (l < 16) {
    #pragma unroll
    for (int qt = 0; qt < 2; ++qt)
      #pragma unroll
      for (int k = 0; k < kK; ++k)
        red[w][qt][lr][k] = pk[qt][k];
  }
  __syncthreads();
  for (int i = t; i < 2 * 16 * kK; i += 256) {
    int qt = i / (16 * kK);
    int rem = i - qt * 16 * kK;
    int lq = rem / kK, k = rem - lq * kK;
    float v = red[0][qt][lq][k] + red[1][qt][lq][k] + red[2][qt][lq][k] + red[3][qt][lq][k];
    int q = qt * 16 + lq;
    pkq[(((size_t)pair * kB + b) * kQ + q) * kK + k] = v * qmask[b * kQ + q];
  }
}

// ---------------- log-pool + dense layers ----------------
__global__ __launch_bounds__(128) void finalize_kernel(
    const float* __restrict__ pkq, const float* __restrict__ qmask,
    const float* __restrict__ dmask, const float* __restrict__ nsp,
    const float* __restrict__ dw, const float* __restrict__ dbp,
    const float* __restrict__ dmw, const float* __restrict__ dmbp,
    const float* __restrict__ dcw, float* __restrict__ out)
{
  const int b = blockIdx.x;
  const int t = threadIdx.x;
  __shared__ float sh[4];
  float dl = 0.f;
  for (int d = t; d < kD; d += 128) dl += dmask[b * kD + d];
  #pragma unroll
  for (int off = 1; off < 64; off <<= 1) dl += __shfl_xor(dl, off);
  if ((t & 63) == 0) sh[t >> 6] = dl;
  __syncthreads();
  const float idl = 1.f / (sh[0] + sh[1]);
  const float sc = nsp[0];
  float ps = 0.f, pm = 0.f;
  for (int i = t; i < 99; i += 128) {
    int pr = i / kK, kk = i - pr * kK;
    const float* base = pkq + ((size_t)pr * kB + b) * kQ * kK + kk;
    float ss = 0.f, sm = 0.f;
    for (int q = 0; q < kQ; ++q) {
      float v = base[q * kK];
      float qq = qmask[b * kQ + q];
      ss += __logf(fmaxf(v, 1e-10f)) * qq;
      sm += __logf(fmaxf(v * idl, 1e-10f)) * qq;
    }
    ps += dw[i] * ss;
    pm += dmw[i] * sm;
  }
  ps *= sc; pm *= sc;
  #pragma unroll
  for (int off = 1; off < 64; off <<= 1) { ps += __shfl_xor(ps, off); pm += __shfl_xor(pm, off); }
  __syncthreads();
  if ((t & 63) == 0) { sh[t >> 6] = ps; sh[2 + (t >> 6)] = pm; }
  __syncthreads();
  if (t == 0) {
    float PS = sh[0] + sh[1] + dbp[0];
    float PM = sh[2] + sh[3] + dmbp[0];
    out[b] = dcw[0] * PS + dcw[1] * PM;
  }
}

} // namespace

extern "C" void kernel_launch(void* const* d_in, const int* in_sizes, int n_in,
                              void* d_out, int out_size, void* d_ws, size_t ws_size,
                              hipStream_t stream) {
  const float* qe  = (const float*)d_in[0];
  const float* de  = (const float*)d_in[1];
  const float* qm  = (const float*)d_in[2];
  const float* dm  = (const float*)d_in[3];
  const float* w1  = (const float*)d_in[4];
  const float* b1  = (const float*)d_in[5];
  const float* w2  = (const float*)d_in[6];
  const float* b2  = (const float*)d_in[7];
  const float* w3  = (const float*)d_in[8];
  const float* b3  = (const float*)d_in[9];
  const float* ns  = (const float*)d_in[10];
  const float* dw  = (const float*)d_in[11];
  const float* db  = (const float*)d_in[12];
  const float* dmw = (const float*)d_in[13];
  const float* dmb = (const float*)d_in[14];
  const float* dcw = (const float*)d_in[15];
  float* out = (float*)d_out;

  char* wsb = (char*)d_ws;
  __bf16* wb  = (__bf16*)wsb;
  __bf16* qnb = (__bf16*)(wsb + QNB_B);
  __bf16* dnb = (__bf16*)(wsb + DNB_B);
  float*  pkq = (float*)(wsb + PKQ_B);

  prep_kernel<<<960, 256, 0, stream>>>(w1, w2, w3, wb);
  conv_fused<<<dim3(17, kB), 256, 0, stream>>>(qe, de, wb, b1, b2, b3, qnb, dnb);
  pool_mfma<<<dim3(9, kB), 256, 0, stream>>>(qnb, dnb, qm, dm, pkq);
  finalize_kernel<<<kB, 128, 0, stream>>>(pkq, qm, dm, ns, dw, db, dmw, dmb, dcw, out);
}